// Round 11
// baseline (3568.827 us; speedup 1.0000x reference)
//
#include <hip/hip_runtime.h>

// Problem constants
#define BB 256
#define SS 1024
#define II 64
#define HH 256
#define OO 24
#define NG 16     // groups (16 batch rows each)
#define NP 16     // parts per group (64 z-cols = 16 h-dims each)
#define BT 16

typedef __attribute__((ext_vector_type(8))) short short8;
typedef __attribute__((ext_vector_type(4))) float f32x4;
typedef unsigned long long ull;

#define H_CAP  8192    // h tag-retry rounds (latches sdead)
#define SP_CAP 16384   // sp spin iterations (latches sdead)

// LDS byte offsets; padded to 96KB to guarantee 1 block/CU
#define A_HI 0          // h hi frags  [8 kstep][64 lane][16B]
#define A_LO 8192
#define E_OF 16384      // energy partials [wave][reg][lane] f32 (4KB)
#define HLOC 20480      // h history ring [3][16][17] f32 (~3.3KB)
#define SMEM_BYTES 98304

#define MFMA(a,b,c) __builtin_amdgcn_mfma_f32_16x16x32_bf16(a,b,c,0,0,0)

__device__ __forceinline__ float fsig(float x)  { return 1.f/(1.f+__expf(-x)); }
__device__ __forceinline__ float ftanh(float x) { return 1.f - 2.f/(__expf(2.f*x)+1.f); }

__device__ __forceinline__ unsigned rne_bf16(float x){
    unsigned u = __float_as_uint(x);
    return (u + 0x7FFFu + ((u>>16)&1u)) >> 16;
}
__device__ __forceinline__ void split_bf(float x, unsigned &hi, unsigned &lo){
    hi = rne_bf16(x);
    lo = rne_bf16(x - __uint_as_float(hi<<16));
}

union U4 { unsigned u[4]; short8 s; };

__device__ __forceinline__ void pack8(const float* v, short8 &H, short8 &L){
    U4 h_, l_;
    #pragma unroll
    for (int i = 0; i < 4; ++i) {
        unsigned a,b,c,d;
        split_bf(v[2*i], a, b); split_bf(v[2*i+1], c, d);
        h_.u[i] = a | (c<<16);
        l_.u[i] = b | (d<<16);
    }
    H = h_.s; L = l_.s;
}

// AGENT-scope relaxed atomics (the only scheme proven deterministic+fast)
__device__ __forceinline__ ull cld(const ull* p){
    return __hip_atomic_load(p, __ATOMIC_RELAXED, __HIP_MEMORY_SCOPE_AGENT);
}
__device__ __forceinline__ void cst(ull* p, ull v){
    __hip_atomic_store(p, v, __ATOMIC_RELAXED, __HIP_MEMORY_SCOPE_AGENT);
}

// ---------------------------------------------------------------------------
// Fused xW + LSTM + attention scores + online-softmax context, MFMA bf16x3.
// grid = 256 (16 groups x 16 parts), block = 256 (4 waves).
// r10 protocol (tagged 8B words, consumer-interleaved hx[par][g][j][tid],
// no flags) with restructured compute:
//  - z-cols remapped so wave w holds all 4 gates of dims 4w..4w+3
//    -> gates via in-wave shuffles, no zl LDS, no cross-wave publish wait
//  - gate-owner lane order chosen so h stores are 64B-chunked (8 chunks/wave)
//  - h word payload = (tag32 | hi16 | lo16): split once at producer
//  - softmax h-history via 3-slot LDS ring (read slot (t-2)%3 != write t%3)
// ---------------------------------------------------------------------------
__global__ __launch_bounds__(256, 1)
void lstm_fused_kernel(const float* __restrict__ x,  const float* __restrict__ Wi,
                       const float* __restrict__ Wh, const float* __restrict__ bias,
                       const float* __restrict__ aW, const float* __restrict__ ab,
                       const float* __restrict__ av,
                       ull* __restrict__ hx, ull* __restrict__ spx,
                       float* __restrict__ ctxg)
{
    __shared__ __align__(16) char smem[SMEM_BYTES];
    __shared__ int sdead;

    const int tid = threadIdx.x;
    const int w = tid >> 6;          // wave
    const int l = tid & 63;
    const int p = blockIdx.x >> 4;   // part
    const int g = blockIdx.x & 15;   // group
    const int b0 = g * BT;

    if (tid == 0) sdead = 0;
    __syncthreads();

    const int n = l & 15;            // C col within tile
    // z-col mapping: wave w covers dims p*16+4w..+3, all 4 gates:
    const int gcol = (n>>2)*256 + p*16 + w*4 + (n&3);

    // score-phase ownership (independent of gate mapping; r10's gb/gd)
    const int sb  = (l>>4)*4 + w;    // batch
    const int sjd = n;               // local dim 0..15

    // gate-phase ownership (chosen for 64B-chunked stores)
    const int cch = l >> 3, t3 = l & 7;
    const int b_g  = (t3<<1) | (cch>>2);        // batch
    const int D_gl = 4*w + (cch&3);             // local dim
    const int breg = ((t3&1)<<1) | (cch>>2);    // source reg index
    const int srcb = ((t3>>1)<<4) | (cch&3);    // shuffle src base
    const int j_pub = ((b_g&1)<<3) | (D_gl&7);
    const int tau   = ((2*p + (D_gl>>3))<<3) | t3;

    // ---- init: pre-split B operands into register fragments --------------
    short8 BwhH[8], BwhL[8];
    #pragma unroll
    for (int ks = 0; ks < 8; ++ks) {
        U4 H, L;
        #pragma unroll
        for (int i2 = 0; i2 < 4; ++i2) {
            int k0 = ks*32 + (l>>4)*8 + i2*2;
            unsigned h0,l0,h1,l1;
            split_bf(Wh[(size_t)k0*1024 + gcol], h0, l0);
            split_bf(Wh[(size_t)(k0+1)*1024 + gcol], h1, l1);
            H.u[i2] = h0 | (h1<<16);
            L.u[i2] = l0 | (l1<<16);
        }
        BwhH[ks] = H.s; BwhL[ks] = L.s;
    }
    short8 BwiH[2], BwiL[2];
    #pragma unroll
    for (int ks = 0; ks < 2; ++ks) {
        U4 H, L;
        #pragma unroll
        for (int i2 = 0; i2 < 4; ++i2) {
            int k0 = ks*32 + (l>>4)*8 + i2*2;
            unsigned h0,l0,h1,l1;
            split_bf(Wi[(size_t)k0*1024 + gcol], h0, l0);
            split_bf(Wi[(size_t)(k0+1)*1024 + gcol], h1, l1);
            H.u[i2] = h0 | (h1<<16);
            L.u[i2] = l0 | (l1<<16);
        }
        BwiH[ks] = H.s; BwiL[ks] = L.s;
    }
    short8 BwaH[2], BwaL[2];
    #pragma unroll
    for (int j = 0; j < 2; ++j) {
        int ks = 2*w + j;     // this wave's energy k-steps
        U4 H, L;
        #pragma unroll
        for (int i2 = 0; i2 < 4; ++i2) {
            int k0 = ks*32 + (l>>4)*8 + i2*2;
            unsigned h0,l0,h1,l1;
            split_bf(aW[(size_t)k0*256 + p*16 + n], h0, l0);
            split_bf(aW[(size_t)(k0+1)*256 + p*16 + n], h1, l1);
            H.u[i2] = h0 | (h1<<16);
            L.u[i2] = l0 | (l1<<16);
        }
        BwaH[j] = H.s; BwaL[j] = L.s;
    }
    const float bb  = bias[gcol];
    const float vj  = av[p*16 + sjd];
    const float abj = ab[p*16 + sjd];

    // consumer mapping (r10): thread tid reads words j=0..15 at hx[..][j][tid]
    const int po    = tid >> 3;
    const int pbase = (tid & 7) * 2;
    const int wa0 = (po>>2)*1024 + ((po&3)*16 + pbase)*16;
    const int wa1 = wa0 + 16;

    const int xb = l & 15;
    const int xoct = l >> 4;

    float c_state = 0.f;
    float m_run = -1.0e30f, l_run = 0.f, ctx = 0.f;

    float* el   = (float*)(smem + E_OF);
    float* hloc = (float*)(smem + HLOC);   // [3][16][17]

    for (int t = 0; t < SS; ++t) {
        const int par = t & 1;
        // ---- x loads -----------------------------------------------------
        const float* xrow = x + ((size_t)(b0 + xb) * SS + t) * II + xoct*8;
        float xv0[8], xv1[8];
        *(float4*)&xv0[0] = *(const float4*)(xrow);
        *(float4*)&xv0[4] = *(const float4*)(xrow + 4);
        *(float4*)&xv1[0] = *(const float4*)(xrow + 32);
        *(float4*)&xv1[4] = *(const float4*)(xrow + 36);

        // ---- issue coalesced tagged h(t-1) loads -------------------------
        ull hv[16]; ull spr = 0;
        const ull* hr = hx + ((size_t)(((t-1)&1)*NG + g) * 16) * 256 + tid;
        if (t > 0) {
            #pragma unroll
            for (int j = 0; j < 16; ++j) hv[j] = cld(hr + j*256);
        }
        ull* spp = spx + (size_t)par*4096 + g*256 + sb*16 + sjd;
        if (t > 1) spr = cld(spp);

        // ---- x pack + x MFMA (overlaps h-load flight) --------------------
        short8 XH0, XL0, XH1, XL1;
        pack8(xv0, XH0, XL0);
        pack8(xv1, XH1, XL1);
        f32x4 zacc = {bb,bb,bb,bb};
        zacc = MFMA(XH0, BwiH[0], zacc);
        zacc = MFMA(XH0, BwiL[0], zacc);
        zacc = MFMA(XL0, BwiH[0], zacc);
        zacc = MFMA(XH1, BwiH[1], zacc);
        zacc = MFMA(XH1, BwiL[1], zacc);
        zacc = MFMA(XL1, BwiH[1], zacc);

        // ---- tag check + coalesced retry rounds --------------------------
        if (t > 0) {
            const unsigned texp = (unsigned)t;   // h(t-1) tagged t
            unsigned need = 0xFFFFu;
            int rounds = 0;
            while (true) {
                unsigned nn = 0;
                #pragma unroll
                for (int e = 0; e < 16; ++e)
                    if (need & (1u<<e))
                        if ((unsigned)(hv[e]>>32) != texp) nn |= (1u<<e);
                need = nn;
                if (!need || sdead) break;
                if (++rounds > H_CAP) { sdead = 1; break; }
                #pragma unroll
                for (int e = 0; e < 16; ++e)
                    if (need & (1u<<e)) hv[e] = cld(hr + e*256);
            }
            // frag build straight from (hi|lo) payloads — bit ops only
            U4 H0u, L0u, H1u, L1u;
            #pragma unroll
            for (int i = 0; i < 4; ++i) {
                unsigned a = (unsigned)hv[2*i],   b_ = (unsigned)hv[2*i+1];
                unsigned c = (unsigned)hv[8+2*i], d_ = (unsigned)hv[9+2*i];
                H0u.u[i] = (a>>16) | (b_ & 0xFFFF0000u);
                L0u.u[i] = (a & 0xFFFFu) | (b_<<16);
                H1u.u[i] = (c>>16) | (d_ & 0xFFFF0000u);
                L1u.u[i] = (c & 0xFFFFu) | (d_<<16);
            }
            *(short8*)(smem + A_HI + wa0) = H0u.s;
            *(short8*)(smem + A_LO + wa0) = L0u.s;
            *(short8*)(smem + A_HI + wa1) = H1u.s;
            *(short8*)(smem + A_LO + wa1) = L1u.s;
        }
        __syncthreads();                                   // barrier A

        // ---- MFMA: z += h@Wh, energy partial -----------------------------
        f32x4 zacc1 = {0.f,0.f,0.f,0.f};
        f32x4 eacc  = {0.f,0.f,0.f,0.f};
        if (t > 0) {
            #pragma unroll
            for (int ks = 0; ks < 8; ++ks) {
                short8 ah = *(const short8*)(smem + A_HI + ks*1024 + l*16);
                short8 al = *(const short8*)(smem + A_LO + ks*1024 + l*16);
                if ((ks & 1) == 0) {
                    zacc = MFMA(ah, BwhH[ks], zacc);
                    zacc = MFMA(ah, BwhL[ks], zacc);
                    zacc = MFMA(al, BwhH[ks], zacc);
                } else {
                    zacc1 = MFMA(ah, BwhH[ks], zacc1);
                    zacc1 = MFMA(ah, BwhL[ks], zacc1);
                    zacc1 = MFMA(al, BwhH[ks], zacc1);
                }
                if ((ks>>1) == w) {
                    int jj = ks & 1;
                    eacc = MFMA(ah, BwaH[jj], eacc);
                    eacc = MFMA(ah, BwaL[jj], eacc);
                    eacc = MFMA(al, BwaH[jj], eacc);
                }
            }
        }

        // ---- gates via in-wave shuffle gather (no LDS, no barrier) -------
        float zs0 = zacc[0]+zacc1[0], zs1 = zacc[1]+zacc1[1];
        float zs2 = zacc[2]+zacc1[2], zs3 = zacc[3]+zacc1[3];
        float zg0,zg1,zg2,zg3;
        #pragma unroll
        for (int q = 0; q < 4; ++q) {
            int srcl = srcb | (q<<2);
            float v0 = __shfl(zs0, srcl);
            float v1 = __shfl(zs1, srcl);
            float v2 = __shfl(zs2, srcl);
            float v3 = __shfl(zs3, srcl);
            float vv = (breg==0)? v0 : (breg==1)? v1 : (breg==2)? v2 : v3;
            if      (q==0) zg0 = vv;
            else if (q==1) zg1 = vv;
            else if (q==2) zg2 = vv;
            else           zg3 = vv;
        }
        float ig = fsig(zg0), fg = fsig(zg1), gv = ftanh(zg2), og = fsig(zg3);
        c_state = fg*c_state + ig*gv;
        float h = og * ftanh(c_state);

        // ---- h history for softmax (3-ring; slot t%3 != read slot) -------
        hloc[((t%3)*16 + b_g)*17 + D_gl] = h;

        // ---- publish h(t) tagged t+1: 64B-chunked per wave ---------------
        {
            unsigned hhi, hlo;
            split_bf(h, hhi, hlo);
            cst(hx + ((size_t)(par*NG + g) * 16 + j_pub) * 256 + tau,
                ((ull)(unsigned)(t+1) << 32) | (ull)((hhi<<16)|hlo));
        }

        // ---- energy partials to LDS, then cross-wave sum -----------------
        if (t > 0) {
            #pragma unroll
            for (int r = 0; r < 4; ++r) el[w*256 + r*64 + l] = eacc[r];
        }
        __syncthreads();                                   // barrier B'

        // ---- score partial t-1, softmax update t-2 (off publish path) ----
        if (t > 0) {
            float e = el[0*256+w*64+l] + el[1*256+w*64+l]
                    + el[2*256+w*64+l] + el[3*256+w*64+l] + abj;
            float scp = vj * ftanh(e);
            scp += __shfl_xor(scp,1); scp += __shfl_xor(scp,2);
            scp += __shfl_xor(scp,4); scp += __shfl_xor(scp,8);
            if (sjd == 0)
                cst(spx + (size_t)((t-1)&1)*4096 + g*256 + sb*16 + p,
                    ((ull)(unsigned)t << 32) | (ull)__float_as_uint(scp));
        }
        if (t > 1) {
            const unsigned texp = (unsigned)(t-1);
            int it = 0;
            while ((unsigned)(spr>>32) != texp) {
                if (sdead || ++it > SP_CAP) { sdead = 1; break; }
                spr = cld(spp);
            }
            float s = __uint_as_float((unsigned)spr);
            s += __shfl_xor(s,1); s += __shfl_xor(s,2);
            s += __shfl_xor(s,4); s += __shfl_xor(s,8);
            float hh = hloc[(((t-2)%3)*16 + sb)*17 + sjd];
            float m_new = fmaxf(m_run, s);
            float sc = __expf(m_run - m_new);
            float wt = __expf(s - m_new);
            l_run = l_run*sc + wt;
            ctx   = ctx*sc + wt*hh;
            m_run = m_new;
        }
    }

    // ---- epilogue A: energy/score for SS-1, softmax update for SS-2 ------
    {
        const ull* hr = hx + ((size_t)(((SS-1)&1)*NG + g) * 16) * 256 + tid;
        ull hv[16];
        #pragma unroll
        for (int j = 0; j < 16; ++j) hv[j] = cld(hr + j*256);
        const unsigned texp = (unsigned)SS;
        unsigned need = 0xFFFFu;
        int rounds = 0;
        while (true) {
            unsigned nn = 0;
            #pragma unroll
            for (int e = 0; e < 16; ++e)
                if (need & (1u<<e))
                    if ((unsigned)(hv[e]>>32) != texp) nn |= (1u<<e);
            need = nn;
            if (!need || sdead) break;
            if (++rounds > H_CAP) { sdead = 1; break; }
            #pragma unroll
            for (int e = 0; e < 16; ++e)
                if (need & (1u<<e)) hv[e] = cld(hr + e*256);
        }
        U4 H0u, L0u, H1u, L1u;
        #pragma unroll
        for (int i = 0; i < 4; ++i) {
            unsigned a = (unsigned)hv[2*i],   b_ = (unsigned)hv[2*i+1];
            unsigned c = (unsigned)hv[8+2*i], d_ = (unsigned)hv[9+2*i];
            H0u.u[i] = (a>>16) | (b_ & 0xFFFF0000u);
            L0u.u[i] = (a & 0xFFFFu) | (b_<<16);
            H1u.u[i] = (c>>16) | (d_ & 0xFFFF0000u);
            L1u.u[i] = (c & 0xFFFFu) | (d_<<16);
        }
        *(short8*)(smem + A_HI + wa0) = H0u.s;
        *(short8*)(smem + A_LO + wa0) = L0u.s;
        *(short8*)(smem + A_HI + wa1) = H1u.s;
        *(short8*)(smem + A_LO + wa1) = L1u.s;
        __syncthreads();

        f32x4 eacc = {0.f,0.f,0.f,0.f};
        #pragma unroll
        for (int ks = 0; ks < 8; ++ks) {
            if ((ks>>1) == w) {
                short8 ah = *(const short8*)(smem + A_HI + ks*1024 + l*16);
                short8 al = *(const short8*)(smem + A_LO + ks*1024 + l*16);
                int jj = ks & 1;
                eacc = MFMA(ah, BwaH[jj], eacc);
                eacc = MFMA(ah, BwaL[jj], eacc);
                eacc = MFMA(al, BwaH[jj], eacc);
            }
        }
        #pragma unroll
        for (int r = 0; r < 4; ++r) el[w*256 + r*64 + l] = eacc[r];
        __syncthreads();

        {   // softmax update for SS-2 (sp slot SS&1, tag SS-1)
            ull* spp2 = spx + (size_t)(SS&1)*4096 + g*256 + sb*16 + sjd;
            ull spr = cld(spp2);
            const unsigned te2 = (unsigned)(SS-1);
            int it = 0;
            while ((unsigned)(spr>>32) != te2) {
                if (sdead || ++it > SP_CAP) { sdead = 1; break; }
                spr = cld(spp2);
            }
            float s = __uint_as_float((unsigned)spr);
            s += __shfl_xor(s,1); s += __shfl_xor(s,2);
            s += __shfl_xor(s,4); s += __shfl_xor(s,8);
            float hh = hloc[(((SS-2)%3)*16 + sb)*17 + sjd];
            float m_new = fmaxf(m_run, s);
            float sc = __expf(m_run - m_new);
            float wt = __expf(s - m_new);
            l_run = l_run*sc + wt;
            ctx   = ctx*sc + wt*hh;
            m_run = m_new;
        }
        // score for SS-1 (tag SS)
        float e = el[0*256+w*64+l] + el[1*256+w*64+l]
                + el[2*256+w*64+l] + el[3*256+w*64+l] + abj;
        float scp = vj * ftanh(e);
        scp += __shfl_xor(scp,1); scp += __shfl_xor(scp,2);
        scp += __shfl_xor(scp,4); scp += __shfl_xor(scp,8);
        if (sjd == 0)
            cst(spx + (size_t)((SS-1)&1)*4096 + g*256 + sb*16 + p,
                ((ull)(unsigned)SS << 32) | (ull)__float_as_uint(scp));
    }

    // ---- epilogue B: softmax update for SS-1, write context --------------
    {
        ull* spp2 = spx + (size_t)((SS-1)&1)*4096 + g*256 + sb*16 + sjd;
        ull spr = cld(spp2);
        const unsigned texp = (unsigned)SS;
        int it = 0;
        while ((unsigned)(spr>>32) != texp) {
            if (sdead || ++it > SP_CAP) { sdead = 1; break; }
            spr = cld(spp2);
        }
        float s = __uint_as_float((unsigned)spr);
        s += __shfl_xor(s,1); s += __shfl_xor(s,2);
        s += __shfl_xor(s,4); s += __shfl_xor(s,8);
        float hh = hloc[(((SS-1)%3)*16 + sb)*17 + sjd];
        float m_new = fmaxf(m_run, s);
        float sc = __expf(m_run - m_new);
        float wt = __expf(s - m_new);
        l_run = l_run*sc + wt;
        ctx   = ctx*sc + wt*hh;

        ctxg[(size_t)(b0+sb)*HH + p*16 + sjd] = ctx / l_run;
    }
}

// ---------------------------------------------------------------------------
__global__ __launch_bounds__(64)
void finalize_kernel(const float* __restrict__ ctxg, const float* __restrict__ fcW,
                     const float* __restrict__ fcb, float* __restrict__ out)
{
    __shared__ float cs[HH];
    const int b = blockIdx.x, tid = threadIdx.x;
    *(float4*)&cs[tid*4] = *(const float4*)&ctxg[(size_t)b*HH + tid*4];
    __syncthreads();
    if (tid < OO) {
        float a = fcb[tid];
        #pragma unroll 8
        for (int d = 0; d < HH; ++d) a = fmaf(cs[d], fcW[d*OO + tid], a);
        out[b*OO + tid] = a;
    }
}

// ---------------------------------------------------------------------------
extern "C" void kernel_launch(void* const* d_in, const int* in_sizes, int n_in,
                              void* d_out, int out_size, void* d_ws, size_t ws_size,
                              hipStream_t stream)
{
    const float* x      = (const float*)d_in[0];
    const float* Wi     = (const float*)d_in[1];
    const float* Wh     = (const float*)d_in[2];
    const float* bias   = (const float*)d_in[3];
    const float* attn_W = (const float*)d_in[4];
    const float* attn_b = (const float*)d_in[5];
    const float* v      = (const float*)d_in[6];
    const float* fc_W   = (const float*)d_in[7];
    const float* fc_b   = (const float*)d_in[8];
    float* out = (float*)d_out;

    // workspace: tagged h ring (1MB, consumer-interleaved) + tagged sp ring + ctx
    ull*   hx   = (ull*)d_ws;                  // 2*NG*16*256 = 131072 ull
    ull*   spx  = hx + 2*NG*16*256;            // 2*NG*256    = 8192 ull
    float* ctxg = (float*)(spx + 8192);        // 65536 floats

    // zero all tags each launch (graph-replay + poison safe)
    hipMemsetAsync(hx, 0, (2*NG*16*256 + 8192) * sizeof(ull), stream);

    lstm_fused_kernel<<<dim3(NG*NP), dim3(256), 0, stream>>>(
        x, Wi, Wh, bias, attn_W, attn_b, v, hx, spx, ctxg);
    finalize_kernel<<<dim3(BB), dim3(64), 0, stream>>>(ctxg, fc_W, fc_b, out);
}